// Round 3
// baseline (4825.666 us; speedup 1.0000x reference)
//
#include <hip/hip_runtime.h>
#include <stdint.h>

// Problem constants
#define Bn 256
#define Cn 512
#define Sn 256
#define En 512
#define Vn 1024
#define ST 16   // s-tile per fused block

// ---------------------------------------------------------------------------
// stats: per (b,g) mean/rstd in fp64, folded into per-(b,c) scale/bias
// ---------------------------------------------------------------------------
__global__ __launch_bounds__(256) void stats_kernel(
    const float* __restrict__ x, const float* __restrict__ gamma,
    const float* __restrict__ beta, float* __restrict__ scale,
    float* __restrict__ bias)
{
  int blk = blockIdx.x;
  int b = blk >> 5, g = blk & 31;
  int tid = threadIdx.x;
  size_t base = ((size_t)(b * Cn + g * 16)) * Sn;
  double s1 = 0.0, s2 = 0.0;
#pragma unroll
  for (int k = 0; k < 16; ++k) {
    float v = x[base + (size_t)k * Sn + tid];
    s1 += v; s2 += (double)v * (double)v;
  }
  for (int off = 32; off > 0; off >>= 1) {
    s1 += __shfl_down(s1, off);
    s2 += __shfl_down(s2, off);
  }
  __shared__ double r1[4], r2[4];
  __shared__ float smean, srstd;
  int w = tid >> 6, lane = tid & 63;
  if (lane == 0) { r1[w] = s1; r2[w] = s2; }
  __syncthreads();
  if (tid == 0) {
    double S1 = r1[0] + r1[1] + r1[2] + r1[3];
    double S2 = r2[0] + r2[1] + r2[2] + r2[3];
    double mean = S1 / 4096.0;
    double var = S2 / 4096.0 - mean * mean;
    double rstd = 1.0 / sqrt(var + 1e-6);
    smean = (float)mean; srstd = (float)rstd;
  }
  __syncthreads();
  if (tid < 16) {
    int c = g * 16 + tid;
    float sc = srstd * gamma[c];
    scale[b * Cn + c] = sc;
    bias[b * Cn + c] = beta[c] - smean * sc;
  }
}

// ---------------------------------------------------------------------------
// e2: |emb_v|^2
// ---------------------------------------------------------------------------
__global__ __launch_bounds__(64) void e2_kernel(const float* __restrict__ emb,
                                                float* __restrict__ e2)
{
  int v = blockIdx.x, lane = threadIdx.x;
  float acc = 0.f;
#pragma unroll
  for (int k = 0; k < En / 64; ++k) {
    float e = emb[(size_t)v * En + lane + k * 64];
    acc += e * e;
  }
  for (int off = 32; off > 0; off >>= 1) acc += __shfl_down(acc, off);
  if (lane == 0) e2[v] = acc;
}

// ---------------------------------------------------------------------------
// R[v][c] = sum_e emb[v][e] * w_post[c][e] + b_post[c]   (1024x512, K=512)
// ---------------------------------------------------------------------------
__global__ __launch_bounds__(256) void r_kernel(
    const float* __restrict__ emb, const float* __restrict__ w_post,
    const float* __restrict__ b_post, float* __restrict__ Rout)
{
  __shared__ float ea[64][33];
  __shared__ float wa[64][33];
  int v0 = (blockIdx.x >> 3) * 64;
  int c0 = (blockIdx.x & 7) * 64;
  int tid = threadIdx.x;
  int tv = tid >> 4, tc = tid & 15;
  float acc[4][4] = {};
  int v_l = tid >> 2, est = (tid & 3) << 3;
  for (int ek = 0; ek < En / 32; ++ek) {
#pragma unroll
    for (int k = 0; k < 8; ++k) {
      ea[v_l][est + k] = emb[(size_t)(v0 + v_l) * En + ek * 32 + est + k];
      wa[v_l][est + k] = w_post[(size_t)(c0 + v_l) * En + ek * 32 + est + k];
    }
    __syncthreads();
#pragma unroll
    for (int e = 0; e < 32; ++e)
#pragma unroll
      for (int i = 0; i < 4; ++i)
#pragma unroll
        for (int j = 0; j < 4; ++j)
          acc[i][j] += ea[tv * 4 + i][e] * wa[tc * 4 + j][e];
    __syncthreads();
  }
#pragma unroll
  for (int i = 0; i < 4; ++i)
#pragma unroll
    for (int j = 0; j < 4; ++j)
      Rout[(size_t)(v0 + tv * 4 + i) * Cn + c0 + tc * 4 + j] =
          acc[i][j] + b_post[c0 + tc * 4 + j];
}

// ---------------------------------------------------------------------------
// fused: GN-affine -> z = W_pre * xn (fp32, LDS) -> fp32 z out
//        -> dist = (|z_s|^2 + |e_v|^2) - 2 * emb . z -> argmin -> tokens
// one block = (b, 16-position s-tile); 512 threads; LDS = 62,016 B
// ---------------------------------------------------------------------------
struct G1 { float wt[64][66]; float xt[64][ST]; };   // 16896 + 4096 = 20992 B
struct G2 { float et[64][66]; };                     // 16896 B
struct RD { float rv[64][16]; int ri[64][16]; };     // 8192 B
union SmemU { G1 g1; G2 g2; RD rd; };

__global__ __launch_bounds__(512) void fused_kernel(
    const float* __restrict__ x, const float* __restrict__ w_pre,
    const float* __restrict__ emb, const float* __restrict__ scale,
    const float* __restrict__ bias, const float* __restrict__ e2,
    float* __restrict__ out_z, float* __restrict__ out_tok,
    int* __restrict__ tok_ws)
{
  __shared__ float zs[En][18];       // 36,864 B
  __shared__ SmemU u;                // 20,992 B
  __shared__ double zpart[16][32];   //  4,096 B
  __shared__ float z2s[16];          //     64 B

  int blk = blockIdx.x;
  int b = blk >> 4, st = blk & 15;
  int s0 = st * ST;
  int tid = threadIdx.x;
  int tv = tid >> 3;             // 0..63
  int ts2 = (tid & 7) << 1;      // 0,2,...,14

  // ---------------- GEMM1: z[e][s] = sum_c w_pre[e][c] * (x*sc + bi) -------
  {
    float acc[8][2] = {};   // [ec][j] ; e = ec*64 + tv
    for (int cc = 0; cc < 8; ++cc) {
      // stage xt (applies GroupNorm affine): 64 c x 16 s
      {
        int c = cc * 64 + tv;
        float sc = scale[b * Cn + c];
        float bi = bias[b * Cn + c];
        float2 xv = *(const float2*)&x[((size_t)(b * Cn + c)) * Sn + s0 + ts2];
        u.g1.xt[tv][ts2]     = xv.x * sc + bi;
        u.g1.xt[tv][ts2 + 1] = xv.y * sc + bi;
      }
#pragma unroll
      for (int ec = 0; ec < 8; ++ec) {
        // stage wt: 64 e-rows x 64 c
        {
          int cst = (tid & 7) << 3;
          const float* src = w_pre + (size_t)(ec * 64 + tv) * Cn + cc * 64 + cst;
          float4 a = *(const float4*)(src);
          float4 b4 = *(const float4*)(src + 4);
          float* dst = &u.g1.wt[tv][cst];
          dst[0] = a.x;  dst[1] = a.y;  dst[2] = a.z;  dst[3] = a.w;
          dst[4] = b4.x; dst[5] = b4.y; dst[6] = b4.z; dst[7] = b4.w;
        }
        __syncthreads();
        float p0 = 0.f, p1 = 0.f;
#pragma unroll 16
        for (int c = 0; c < 64; c += 2) {
          float2 w  = *(const float2*)&u.g1.wt[tv][c];
          float2 xa = *(const float2*)&u.g1.xt[c][ts2];
          float2 xb = *(const float2*)&u.g1.xt[c + 1][ts2];
          p0 += w.x * xa.x + w.y * xb.x;
          p1 += w.x * xa.y + w.y * xb.y;
        }
        acc[ec][0] += p0;
        acc[ec][1] += p1;
        __syncthreads();
      }
    }
#pragma unroll
    for (int ec = 0; ec < 8; ++ec) {
      int e = ec * 64 + tv;
      zs[e][ts2]     = acc[ec][0];
      zs[e][ts2 + 1] = acc[ec][1];
    }
  }
  __syncthreads();

  // write z (fp32) to d_out: 512 e x 16 s
#pragma unroll
  for (int k = 0; k < (En * ST) / 512; ++k) {
    int idx = k * 512 + tid;
    int e = idx >> 4, s = idx & 15;
    out_z[((size_t)(b * En + e)) * Sn + s0 + s] = zs[e][s];
  }

  // ---------------- z2[s] = |z_s|^2 (fp64 partials) ------------------------
  {
    int s = tid & 15, seg = tid >> 4;   // seg 0..31
    double p = 0.0;
#pragma unroll
    for (int k = 0; k < 16; ++k) {
      float zv = zs[seg * 16 + k][s];
      p += (double)zv * (double)zv;
    }
    zpart[s][seg] = p;
  }
  __syncthreads();
  if (tid < 16) {
    double a = 0.0;
#pragma unroll
    for (int seg = 0; seg < 32; ++seg) a += zpart[tid][seg];
    z2s[tid] = (float)a;
  }
  __syncthreads();

  // ---------------- GEMM2 + argmin: dist = (z2+e2) - 2*<emb_v, z> ----------
  float z2a = z2s[ts2], z2b = z2s[ts2 + 1];
  float bv0 = INFINITY, bv1 = INFINITY;
  int bi0 = 0, bi1 = 0;
  for (int vc = 0; vc < 16; ++vc) {
    float a0 = 0.f, a1 = 0.f;
    for (int ech = 0; ech < 8; ++ech) {
      // stage et: 64 v-rows x 64 e
      {
        int est = (tid & 7) << 3;
        const float* src = emb + (size_t)(vc * 64 + tv) * En + ech * 64 + est;
        float4 a = *(const float4*)(src);
        float4 b4 = *(const float4*)(src + 4);
        float* dst = &u.g2.et[tv][est];
        dst[0] = a.x;  dst[1] = a.y;  dst[2] = a.z;  dst[3] = a.w;
        dst[4] = b4.x; dst[5] = b4.y; dst[6] = b4.z; dst[7] = b4.w;
      }
      __syncthreads();
      float p0 = 0.f, p1 = 0.f;
#pragma unroll 16
      for (int e = 0; e < 64; e += 2) {
        int eg = ech * 64 + e;
        float2 ev = *(const float2*)&u.g2.et[tv][e];
        float2 za = *(const float2*)&zs[eg][ts2];
        float2 zb = *(const float2*)&zs[eg + 1][ts2];
        p0 += ev.x * za.x + ev.y * zb.x;
        p1 += ev.x * za.y + ev.y * zb.y;
      }
      a0 += p0; a1 += p1;
      __syncthreads();
    }
    int v = vc * 64 + tv;
    float ee = e2[v];
    float t0 = z2a + ee;
    float t1 = z2b + ee;
    float sc0 = t0 - 2.f * a0;
    float sc1 = t1 - 2.f * a1;
    if (sc0 < bv0) { bv0 = sc0; bi0 = v; }   // strict <, v ascending per thread
    if (sc1 < bv1) { bv1 = sc1; bi1 = v; }
  }

  // cross-thread argmin reduce per s column (lexicographic: value, then index)
  u.rd.rv[tv][ts2] = bv0; u.rd.rv[tv][ts2 + 1] = bv1;
  u.rd.ri[tv][ts2] = bi0; u.rd.ri[tv][ts2 + 1] = bi1;
  __syncthreads();
  if (tid < ST) {
    float bvv = INFINITY; int bii = 0;
    for (int t = 0; t < 64; ++t) {
      float vv = u.rd.rv[t][tid]; int ii = u.rd.ri[t][tid];
      if (vv < bvv || (vv == bvv && ii < bii)) { bvv = vv; bii = ii; }
    }
    tok_ws[b * Sn + s0 + tid] = bii;
    out_tok[b * Sn + s0 + tid] = (float)bii;
  }
}

// ---------------------------------------------------------------------------
// gather: z_q[b][e][s] = emb[tok][e] ; rec[b][c][s] = R[tok][c]
// ---------------------------------------------------------------------------
__global__ __launch_bounds__(256) void gather_kernel(
    const int* __restrict__ tok, const float* __restrict__ emb,
    const float* __restrict__ Rt, float* __restrict__ out_zq,
    float* __restrict__ out_rec)
{
  int bq = blockIdx.x;
  int b = bq >> 2, p = bq & 3;
  int s = threadIdx.x;
  unsigned tu = (unsigned)tok[b * Sn + s];
  if (tu > 1023u) tu = 0u;   // defensive clamp: garbage tokens stay in-bounds
  const float* erow = emb + (size_t)tu * En;
  const float* rrow = Rt + (size_t)tu * Cn;
#pragma unroll 4
  for (int r = 0; r < 128; ++r) {
    int e = p * 128 + r;
    out_zq[((size_t)(b * En + e)) * Sn + s] = erow[e];
    out_rec[((size_t)(b * Cn + e)) * Sn + s] = rrow[e];
  }
}

// ---------------------------------------------------------------------------
extern "C" void kernel_launch(void* const* d_in, const int* in_sizes, int n_in,
                              void* d_out, int out_size, void* d_ws, size_t ws_size,
                              hipStream_t stream) {
  const float* x      = (const float*)d_in[0];
  const float* gamma  = (const float*)d_in[1];
  const float* beta   = (const float*)d_in[2];
  const float* w_pre  = (const float*)d_in[3];
  const float* emb    = (const float*)d_in[4];
  const float* w_post = (const float*)d_in[5];
  const float* b_post = (const float*)d_in[6];

  float* out     = (float*)d_out;
  float* out_z   = out;
  float* out_zq  = out + (size_t)Bn * En * Sn;
  float* out_tok = out_zq + (size_t)Bn * En * Sn;
  float* out_rec = out_tok + (size_t)Bn * Sn;

  float* scale = (float*)d_ws;                  // [256*512]
  float* bias  = scale + Bn * Cn;               // [256*512]
  float* e2    = bias + Bn * Cn;                // [1024]
  float* R     = e2 + Vn;                       // [1024*512]
  int* tokw    = (int*)(R + (size_t)Vn * Cn);   // [65536]

  hipMemsetAsync(tokw, 0, (size_t)Bn * Sn * sizeof(int), stream);  // defensive
  stats_kernel<<<Bn * 32, 256, 0, stream>>>(x, gamma, beta, scale, bias);
  e2_kernel<<<Vn, 64, 0, stream>>>(emb, e2);
  r_kernel<<<128, 256, 0, stream>>>(emb, w_post, b_post, R);
  fused_kernel<<<Bn * 16, 512, 0, stream>>>(x, w_pre, emb, scale, bias, e2,
                                            out_z, out_tok, tokw);
  gather_kernel<<<Bn * 4, 256, 0, stream>>>(tokw, emb, R, out_zq, out_rec);
}